// Round 9
// baseline (431.966 us; speedup 1.0000x reference)
//
#include <hip/hip_runtime.h>
#include <hip/hip_bf16.h>

// CrossChannelAttention: B=2, C=64, H=W=96 -> N=9216, NF=192, RD=24.
// k_qkv (MFMA projections) -> k_attn (S key-segments, flash partials) ->
// k_comb (sum/normalize/residual).
// k_attn v9 = v8 skeleton (K global->regs, P dbuf, one barrier/iter,
// QK(it+1) pipelined against PV(it)) with:
//   - PV via MX mfma_scale_f32_16x16x128_f8f6f4 (scales=1.0): 12 MFMAs/wave
//     instead of 48, no intra-iter acc chains.  (layout verified in r7)
//   - s_setprio(1) around the PV MFMA cluster (T5).
// Regs ~118 @ (512,4)=128; spill alarm = FETCH/WRITE GB-scale.

#define NPIX 9216
#define NKT 144     // 64-key tiles (k_qkv granularity)
#define QT128 72    // 128-row q-tiles per batch

typedef unsigned short ushort_t;
typedef unsigned long long u64;
typedef __attribute__((ext_vector_type(8))) short bf16x8;
typedef __attribute__((ext_vector_type(4))) float f32x4;
typedef __attribute__((ext_vector_type(16))) float f32x16;
typedef __attribute__((ext_vector_type(8))) int int8v;
typedef __attribute__((ext_vector_type(4))) unsigned int uint4v;

__device__ inline ushort_t f2bf(float x) {
  __hip_bfloat16 h = __float2bfloat16(x);
  return *reinterpret_cast<ushort_t*>(&h);
}
__device__ inline float bf2f(ushort_t u) {
  unsigned v = ((unsigned)u) << 16;
  return *reinterpret_cast<float*>(&v);
}
__device__ inline float fast_exp2(float x) {
#if __has_builtin(__builtin_amdgcn_exp2f)
  return __builtin_amdgcn_exp2f(x);
#else
  return exp2f(x);
#endif
}
__device__ inline void gload_lds16(const void* g, void* l) {
  __builtin_amdgcn_global_load_lds(
      (const __attribute__((address_space(1))) void*)g,
      (__attribute__((address_space(3))) void*)l, 16, 0, 0);
}
__device__ inline int8v mk8(uint4v lo, uint4v hi) {
  int8v r;
  r[0] = (int)lo[0]; r[1] = (int)lo[1]; r[2] = (int)lo[2]; r[3] = (int)lo[3];
  r[4] = (int)hi[0]; r[5] = (int)hi[1]; r[6] = (int)hi[2]; r[7] = (int)hi[3];
  return r;
}

// ---------------- kernel 0: pack W_cat (256x192 bf16) + bias_cat ----------
__global__ void k_prep(const float* __restrict__ Wq, const float* __restrict__ bq,
                       const float* __restrict__ Wk, const float* __restrict__ bk,
                       const float* __restrict__ Wv, const float* __restrict__ bv,
                       ushort_t* __restrict__ Wbf, float* __restrict__ bias) {
  const float LOG2E = 1.4426950408889634f;
  int idx = blockIdx.x * 256 + threadIdx.x;
  if (idx < 256 * 192) {
    int o = idx / 192, c = idx % 192;
    float v = 0.f;
    if (o < 24) v = Wq[o * 192 + c] * LOG2E;
    else if (o < 48) v = Wk[(o - 24) * 192 + c];
    else if (o < 240) v = Wv[(o - 48) * 192 + c];
    Wbf[idx] = f2bf(v);
  }
  if (idx < 256) {
    float v = 0.f;
    if (idx < 24) v = bq[idx] * LOG2E;
    else if (idx < 48) v = bk[idx - 24];
    else if (idx < 240) v = bv[idx - 48];
    bias[idx] = v;
  }
}

// ---------------- kernel 1: qkv = W_cat . rgb  (MFMA 32x32x16 bf16) -------
// q_ws,k_ws: (B,N,32) bf16 rows (cols 24..31 zeroed). v_ws: (B,192,N) fp8 e4m3.
__global__ __launch_bounds__(256, 2)
void k_qkv(const float* __restrict__ rIn, const float* __restrict__ gIn,
           const float* __restrict__ bIn,
           const ushort_t* __restrict__ Wbf, const float* __restrict__ bias,
           ushort_t* __restrict__ q_ws, ushort_t* __restrict__ k_ws,
           unsigned char* __restrict__ v_ws) {
  __shared__ __align__(16) ushort_t lds[64 * 200];  // [n][c] transposed tile
  int blk = blockIdx.x;
  int bb = blk / NKT, nt = blk % NKT;
  int n0 = nt * 64;
  int t = threadIdx.x;
  {
    int n4 = (t & 15) * 4;
    int c0 = (t >> 4) * 2;
#pragma unroll
    for (int it = 0; it < 6; ++it) {
      int c = c0 + it * 32;
      int color = c >> 6, cw = c & 63;
      const float* base = color == 0 ? rIn : (color == 1 ? gIn : bIn);
      const float* p0 = base + ((size_t)bb * 64 + cw) * NPIX + n0 + n4;
      float4 va = *(const float4*)p0;
      float4 vb = *(const float4*)(p0 + NPIX);
      const float* ap = (const float*)&va;
      const float* bp = (const float*)&vb;
#pragma unroll
      for (int j = 0; j < 4; ++j) {
        unsigned u = ((unsigned)f2bf(bp[j]) << 16) | (unsigned)f2bf(ap[j]);
        *(unsigned*)((char*)lds + (size_t)((n4 + j) * 200 + c) * 2) = u;
      }
    }
  }
  __syncthreads();
  int w = t >> 6, l = t & 63, lo = l & 31, h = l >> 5;
  f32x16 acc[2][2] = {{{}, {}}, {{}, {}}};
  int oG[2] = {(2 * w + 0) * 32 + lo, (2 * w + 1) * 32 + lo};
#pragma unroll 1
  for (int cc = 0; cc < 12; ++cc) {
    bf16x8 af[2], bfr[2];
#pragma unroll
    for (int i = 0; i < 2; ++i)
      af[i] = *(const bf16x8*)((const char*)Wbf + (size_t)oG[i] * 384 + cc * 32 + 16 * h);
#pragma unroll
    for (int ns = 0; ns < 2; ++ns)
      bfr[ns] = *(const bf16x8*)((const char*)lds + (size_t)(ns * 32 + lo) * 400 + cc * 32 + 16 * h);
#pragma unroll
    for (int i = 0; i < 2; ++i)
#pragma unroll
      for (int ns = 0; ns < 2; ++ns)
        acc[i][ns] = __builtin_amdgcn_mfma_f32_32x32x16_bf16(af[i], bfr[ns], acc[i][ns], 0, 0, 0);
  }
#pragma unroll
  for (int i = 0; i < 2; ++i) {
    int o = oG[i];
    float bv = bias[o];
#pragma unroll
    for (int ns = 0; ns < 2; ++ns) {
      if (o < 32) {
#pragma unroll
        for (int r = 0; r < 16; ++r) {
          int n = n0 + ns * 32 + (r & 3) + 8 * (r >> 2) + 4 * h;
          ushort_t val = (o < 24) ? f2bf(acc[i][ns][r] + bv) : (ushort_t)0;
          q_ws[((size_t)bb * NPIX + n) * 32 + o] = val;
        }
      }
      if (o >= 24 && o < 56) {
        int kc = o - 24;
#pragma unroll
        for (int r = 0; r < 16; ++r) {
          int n = n0 + ns * 32 + (r & 3) + 8 * (r >> 2) + 4 * h;
          ushort_t val = (o < 48) ? f2bf(acc[i][ns][r] + bv) : (ushort_t)0;
          k_ws[((size_t)bb * NPIX + n) * 32 + kc] = val;
        }
      }
      if (o >= 48 && o < 240) {
        int vc = o - 48;
#pragma unroll
        for (int g2 = 0; g2 < 4; ++g2) {
          int r = g2 * 4;
          int n = n0 + ns * 32 + 8 * g2 + 4 * h;
          unsigned wd = (unsigned)__builtin_amdgcn_cvt_pk_fp8_f32(
              acc[i][ns][r] + bv, acc[i][ns][r + 1] + bv, 0, false);
          wd = (unsigned)__builtin_amdgcn_cvt_pk_fp8_f32(
              acc[i][ns][r + 2] + bv, acc[i][ns][r + 3] + bv, (int)wd, true);
          *(unsigned*)(v_ws + ((size_t)bb * 192 + vc) * NPIX + n) = wd;
        }
      }
    }
  }
}

// ---------------- kernel 2: flash attention, one key segment --------------
// LDS (81920B): V dbuf [192 c][128B] @0/@24576 (16B chunk s stored at s^(c&7));
//               P dbuf [128 q][128B fp8] @49152/@65536 (16B chunk kc at kc^(q&7)).
// K straight from global into regs (coalesced, L2-resident).
__global__ __launch_bounds__(512, 4)
void k_attn(const ushort_t* __restrict__ q_ws, const ushort_t* __restrict__ k_ws,
            const unsigned char* __restrict__ v_ws,
            ushort_t* __restrict__ opart, float* __restrict__ lpart,
            int S, int ktPer) {
  __shared__ __align__(16) char smem[81920];
  int id = blockIdx.x;
  int twoS = 2 * S;
  int e = id % twoS, qt = id / twoS;  // id%8 ~ XCD -> per-XCD K/V L2 locality
  int bb = e / S, sg = e % S;
  int q0 = qt * 128;
  int t = threadIdx.x, w = t >> 6, l = t & 63, ql = l & 15, g = l >> 4;
  int ks = w & 3, qh = w >> 2;        // QK roles: keys 32ks.., q 64qh..
  int qgrp = w & 1, cgrp = w >> 1;    // PV roles: 64 q x 48 c

  const char* qb = (const char*)q_ws + (size_t)bb * NPIX * 64;
  const char* kb = (const char*)k_ws + (size_t)bb * NPIX * 64;
  const unsigned char* vb = v_ws + (size_t)bb * 192 * NPIX;

  // Q B-frags: q = q0 + qh*64 + 16j + ql, d-chunk g (16 VGPR)
  bf16x8 qf[4];
#pragma unroll
  for (int j = 0; j < 4; ++j)
    qf[j] = *(const bf16x8*)(qb + (size_t)(q0 + qh * 64 + j * 16 + ql) * 64 + g * 16);

  // V staging source offsets (swizzle folded into source; LDS dest linear)
  int vgo[3];
#pragma unroll
  for (int i = 0; i < 3; ++i) {
    int idx = i * 512 + t;
    int c = idx >> 3, s8 = idx & 7;
    vgo[i] = c * NPIX + ((s8 ^ (c & 7)) << 4);
  }
  // K global read base: key = 32ks + 16a + ql, chunk g
  const char* kbw = kb + (size_t)(ks * 32 + ql) * 64 + g * 16;  // + tile*8192 + a*1024
  // P write offset: row qh*64+16j+ql, chunk (2ks+a)^(ql&7), dword g
  int pwO = (qh * 64 + ql) * 128 + 4 * g;                       // + j*2048 + cswz
  // PV read bases
  int paO = (qgrp * 64 + ql) * 128;                             // + qs*2048 + xo
  int vrO = (cgrp * 48 + ql) * 128;                             // + ct*2048 + xo
  int xo0 = ((g << 1) ^ (ql & 7)) << 4;                         // MX chunk 2g
  int xo1 = xo0 ^ 16;                                           // MX chunk 2g+1

  int kbase = sg * ktPer * 128;

  f32x4 oacc[12];  // [qs*3 + ct]
#pragma unroll
  for (int i = 0; i < 12; ++i) oacc[i] = f32x4{0.f, 0.f, 0.f, 0.f};
  float ls[4] = {0.f, 0.f, 0.f, 0.f};

#define QK_PHASE(PBASE)                                                        \
  {                                                                            \
    _Pragma("unroll")                                                          \
    for (int a = 0; a < 2; ++a) {                                              \
      int cswz = ((2 * ks + a) ^ (ql & 7)) << 4;                               \
      _Pragma("unroll")                                                        \
      for (int j = 0; j < 4; ++j) {                                            \
        f32x4 s = f32x4{0.f, 0.f, 0.f, 0.f};                                   \
        s = __builtin_amdgcn_mfma_f32_16x16x32_bf16(a ? kf1 : kf0, qf[j], s,   \
                                                    0, 0, 0);                  \
        float p0 = fast_exp2(s[0]), p1 = fast_exp2(s[1]);                      \
        float p2 = fast_exp2(s[2]), p3 = fast_exp2(s[3]);                      \
        ls[j] += (p0 + p1) + (p2 + p3);                                        \
        unsigned uu =                                                          \
            (unsigned)__builtin_amdgcn_cvt_pk_fp8_f32(p0, p1, 0, false);       \
        uu = (unsigned)__builtin_amdgcn_cvt_pk_fp8_f32(p2, p3, (int)uu, true); \
        *(unsigned*)(smem + (PBASE) + pwO + j * 2048 + cswz) = uu;             \
      }                                                                        \
    }                                                                          \
  }

  {  // prologue: stage V(0), load K(0) frags, QK(0) -> P[0]
    const unsigned char* vp = vb + kbase;
#pragma unroll
    for (int i = 0; i < 3; ++i)
      gload_lds16(vp + vgo[i], smem + i * 8192 + w * 1024);
    const char* ka = kbw + (size_t)kbase * 64;
    bf16x8 kf0 = *(const bf16x8*)ka;
    bf16x8 kf1 = *(const bf16x8*)(ka + 1024);
    QK_PHASE(49152)
  }
  __syncthreads();  // P[0] visible; V(0) DMA drained

#pragma unroll 1
  for (int it = 0; it < ktPer; ++it) {
    int par = it & 1;
    bf16x8 kf0, kf1;
    bool more = (it + 1 < ktPer);
    if (more) {  // K(it+1) -> regs; V(it+1) -> V[par^1] (DMA)
      const char* ka = kbw + (size_t)(kbase + (it + 1) * 128) * 64;
      kf0 = *(const bf16x8*)ka;
      kf1 = *(const bf16x8*)(ka + 1024);
      const unsigned char* vp = vb + kbase + (it + 1) * 128;
#pragma unroll
      for (int i = 0; i < 3; ++i)
        gload_lds16(vp + vgo[i], smem + (par ^ 1) * 24576 + i * 8192 + w * 1024);
    }
    // ---- PV(it): 64 q x 48 c per wave, MX K=128 (scales=1.0), P[par]/V[par]
    {
      const char* pbuf = smem + 49152 + par * 16384 + paO;
      const char* vbuf = smem + par * 24576 + vrO;
      int8v Bv0, Bv1, Bv2;
      {
        uint4v b0l = *(const uint4v*)(vbuf + 0 * 2048 + xo0);
        uint4v b0h = *(const uint4v*)(vbuf + 0 * 2048 + xo1);
        uint4v b1l = *(const uint4v*)(vbuf + 1 * 2048 + xo0);
        uint4v b1h = *(const uint4v*)(vbuf + 1 * 2048 + xo1);
        uint4v b2l = *(const uint4v*)(vbuf + 2 * 2048 + xo0);
        uint4v b2h = *(const uint4v*)(vbuf + 2 * 2048 + xo1);
        Bv0 = mk8(b0l, b0h); Bv1 = mk8(b1l, b1h); Bv2 = mk8(b2l, b2h);
      }
      __builtin_amdgcn_s_setprio(1);
#pragma unroll
      for (int qs = 0; qs < 4; ++qs) {
        uint4v alo = *(const uint4v*)(pbuf + qs * 2048 + xo0);
        uint4v ahi = *(const uint4v*)(pbuf + qs * 2048 + xo1);
        int8v Av = mk8(alo, ahi);
        oacc[qs * 3 + 0] = __builtin_amdgcn_mfma_scale_f32_16x16x128_f8f6f4(
            Av, Bv0, oacc[qs * 3 + 0], 0, 0, 0, 0x7F7F7F7F, 0, 0x7F7F7F7F);
        oacc[qs * 3 + 1] = __builtin_amdgcn_mfma_scale_f32_16x16x128_f8f6f4(
            Av, Bv1, oacc[qs * 3 + 1], 0, 0, 0, 0x7F7F7F7F, 0, 0x7F7F7F7F);
        oacc[qs * 3 + 2] = __builtin_amdgcn_mfma_scale_f32_16x16x128_f8f6f4(
            Av, Bv2, oacc[qs * 3 + 2], 0, 0, 0, 0x7F7F7F7F, 0, 0x7F7F7F7F);
      }
      __builtin_amdgcn_s_setprio(0);
    }
    // ---- QK(it+1) -> P[par^1] (independent of PV(it)) ----
    if (more) QK_PHASE(49152 + (par ^ 1) * 16384)
    __syncthreads();  // P[par^1] visible; V(it+1) DMA drained; P/V[par] free
  }
#undef QK_PHASE

  // ---- lsum: reduce over g (shfl), then over 4 ks-waves via LDS ----
  float* tbl = (float*)(smem + 49152);  // [8 waves][64 q] overlays P
#pragma unroll
  for (int j = 0; j < 4; ++j) {
    float v = ls[j];
    v += __shfl_xor(v, 16);
    v += __shfl_xor(v, 32);
    if (l < 16) tbl[w * 64 + j * 16 + ql] = v;
  }
  __syncthreads();
  if (t < 128) {
    int qhh = t >> 6, qr = t & 63;
    float s = 0.f;
#pragma unroll
    for (int k2 = 0; k2 < 4; ++k2) s += tbl[(qhh * 4 + k2) * 64 + qr];
    lpart[(size_t)(sg * 2 + bb) * NPIX + q0 + t] = s;
  }

  // ---- store O partials: lane holds O[q=qs*16+4g+r][c=cgrp*48+ct*16+ql] ----
  ushort_t* ob = opart + (size_t)(sg * 2 + bb) * 192 * NPIX;
#pragma unroll
  for (int qs = 0; qs < 4; ++qs)
#pragma unroll
    for (int ct = 0; ct < 3; ++ct) {
      f32x4 o = oacc[qs * 3 + ct];
      u64 pk = (u64)f2bf(o[0]) | ((u64)f2bf(o[1]) << 16)
             | ((u64)f2bf(o[2]) << 32) | ((u64)f2bf(o[3]) << 48);
      *(u64*)(ob + (size_t)(cgrp * 48 + ct * 16 + ql) * NPIX
              + q0 + qgrp * 64 + qs * 16 + 4 * g) = pk;
    }
}

// ---------------- kernel 3: combine partials + residual -------------------
__global__ __launch_bounds__(256, 8)
void k_comb(const ushort_t* __restrict__ opart, const float* __restrict__ lpart,
            const float* __restrict__ rIn, const float* __restrict__ gIn,
            const float* __restrict__ bIn, float* __restrict__ out, int S) {
  int tg = blockIdx.x * 256 + threadIdx.x;   // 442368 threads: (bb,c) x n8
  int n8 = tg % 1152, row = tg / 1152;       // row in [0,384)
  int bb = row / 192, c = row % 192;
  int n = n8 * 8;
  float acc[8] = {0.f, 0.f, 0.f, 0.f, 0.f, 0.f, 0.f, 0.f};
  float lt[8] = {0.f, 0.f, 0.f, 0.f, 0.f, 0.f, 0.f, 0.f};
#pragma unroll 1
  for (int sg = 0; sg < S; ++sg) {
    const ushort_t* p = opart + ((size_t)(sg * 2 + bb) * 192 + c) * NPIX + n;
    uint4v u = *(const uint4v*)p;
    const ushort_t* us = (const ushort_t*)&u;
#pragma unroll
    for (int j = 0; j < 8; ++j) acc[j] += bf2f(us[j]);
    const float* lp = lpart + (size_t)(sg * 2 + bb) * NPIX + n;
    float4 l0 = *(const float4*)lp;
    float4 l1 = *(const float4*)(lp + 4);
    lt[0] += l0.x; lt[1] += l0.y; lt[2] += l0.z; lt[3] += l0.w;
    lt[4] += l1.x; lt[5] += l1.y; lt[6] += l1.z; lt[7] += l1.w;
  }
  int color = c >> 6, cw = c & 63;
  const float* base = color == 0 ? rIn : (color == 1 ? gIn : bIn);
  const float* rp = base + ((size_t)bb * 64 + cw) * NPIX + n;
  float4 r0 = *(const float4*)rp;
  float4 r1 = *(const float4*)(rp + 4);
  float o[8];
  o[0] = r0.x + acc[0] / lt[0]; o[1] = r0.y + acc[1] / lt[1];
  o[2] = r0.z + acc[2] / lt[2]; o[3] = r0.w + acc[3] / lt[3];
  o[4] = r1.x + acc[4] / lt[4]; o[5] = r1.y + acc[5] / lt[5];
  o[6] = r1.z + acc[6] / lt[6]; o[7] = r1.w + acc[7] / lt[7];
  float* op = out + ((size_t)(color * 2 + bb) * 64 + cw) * NPIX + n;
  *(float4*)op = {o[0], o[1], o[2], o[3]};
  *(float4*)(op + 4) = {o[4], o[5], o[6], o[7]};
}

// ---------------- launcher -------------------------------------------------
extern "C" void kernel_launch(void* const* d_in, const int* in_sizes, int n_in,
                              void* d_out, int out_size, void* d_ws, size_t ws_size,
                              hipStream_t stream) {
  const float* r  = (const float*)d_in[0];
  const float* g  = (const float*)d_in[1];
  const float* b  = (const float*)d_in[2];
  const float* Wq = (const float*)d_in[3];
  const float* bq = (const float*)d_in[4];
  const float* Wk = (const float*)d_in[5];
  const float* bk = (const float*)d_in[6];
  const float* Wv = (const float*)d_in[7];
  const float* bv = (const float*)d_in[8];

  char* ws = (char*)d_ws;
  ushort_t* Wbf = (ushort_t*)(ws);                       //  98304 B
  float* bias   = (float*)(ws + 98304);                  //   1024 B
  ushort_t* q_ws = (ushort_t*)(ws + 99328);              // 1179648 B
  ushort_t* k_ws = (ushort_t*)(ws + 99328 + 1179648);    // 1179648 B
  unsigned char* v_ws = (unsigned char*)(ws + 99328 + 2 * 1179648);  // 3538944 B
  const size_t qkvEnd = 99328 + 2 * 1179648 + 3538944;   // 5997568
  const size_t perS = (size_t)2 * 192 * NPIX * 2 + (size_t)2 * NPIX * 4;  // 7151616

  int S = 8;
  while (S > 1 && qkvEnd + (size_t)S * perS > ws_size) S >>= 1;
  size_t opartSz = (size_t)S * 2 * 192 * NPIX * 2;
  ushort_t* opart = (ushort_t*)(ws + qkvEnd);
  float* lpart = (float*)(ws + qkvEnd + opartSz);

  k_prep<<<192, 256, 0, stream>>>(Wq, bq, Wk, bk, Wv, bv, Wbf, bias);
  k_qkv<<<2 * NKT, 256, 0, stream>>>(r, g, b, Wbf, bias, q_ws, k_ws, v_ws);
  k_attn<<<QT128 * 2 * S, 512, 0, stream>>>(q_ws, k_ws, v_ws, opart, lpart, S, QT128 / S);
  k_comb<<<1728, 256, 0, stream>>>(opart, lpart, r, g, b, (float*)d_out, S);
}

// Round 10
// 116.207 us; speedup vs baseline: 3.7172x; 3.7172x over previous
//
#include <hip/hip_runtime.h>
#include <hip/hip_bf16.h>

// CrossChannelAttention: B=2, C=64, H=W=96 -> N=9216, NF=192, RD=24.
// k_qkv (MFMA projections) -> k_attn (S key-segments, flash partials) ->
// k_comb (sum/normalize/residual).
// k_attn v10: Q-tile 96, 64-key tiles, 3 blocks/CU (the v8 latency fix).
//   512 thr = 8 waves. QK: wave (ks,qh) = keys 16ks.. x q 48qh.. ; K from
//   global to regs; exp -> fp8 P to LDS. PV: waves = 2 qg(48q) x 4 cg(48c),
//   18x fp8 16x16x32 MFMA. P dbuf, one barrier/iter, QK(it+1) || PV(it).
//   LDS 36KB (V dbuf 24K + P dbuf 12K); regs ~80 @ (512,6)=85.
//   Spill alarm = FETCH/WRITE GB-scale (MX r3/r7/r9 lesson).

#define NPIX 9216
#define NKT 144     // 64-key tiles (k_qkv granularity)
#define QT96 96     // 96-row q-tiles per batch

typedef unsigned short ushort_t;
typedef unsigned long long u64;
typedef __attribute__((ext_vector_type(8))) short bf16x8;
typedef __attribute__((ext_vector_type(4))) float f32x4;
typedef __attribute__((ext_vector_type(16))) float f32x16;
typedef __attribute__((ext_vector_type(4))) unsigned int uint4v;

__device__ inline ushort_t f2bf(float x) {
  __hip_bfloat16 h = __float2bfloat16(x);
  return *reinterpret_cast<ushort_t*>(&h);
}
__device__ inline float bf2f(ushort_t u) {
  unsigned v = ((unsigned)u) << 16;
  return *reinterpret_cast<float*>(&v);
}
__device__ inline float fast_exp2(float x) {
#if __has_builtin(__builtin_amdgcn_exp2f)
  return __builtin_amdgcn_exp2f(x);
#else
  return exp2f(x);
#endif
}
__device__ inline void gload_lds16(const void* g, void* l) {
  __builtin_amdgcn_global_load_lds(
      (const __attribute__((address_space(1))) void*)g,
      (__attribute__((address_space(3))) void*)l, 16, 0, 0);
}

// ---------------- kernel 0: pack W_cat (256x192 bf16) + bias_cat ----------
__global__ void k_prep(const float* __restrict__ Wq, const float* __restrict__ bq,
                       const float* __restrict__ Wk, const float* __restrict__ bk,
                       const float* __restrict__ Wv, const float* __restrict__ bv,
                       ushort_t* __restrict__ Wbf, float* __restrict__ bias) {
  const float LOG2E = 1.4426950408889634f;
  int idx = blockIdx.x * 256 + threadIdx.x;
  if (idx < 256 * 192) {
    int o = idx / 192, c = idx % 192;
    float v = 0.f;
    if (o < 24) v = Wq[o * 192 + c] * LOG2E;
    else if (o < 48) v = Wk[(o - 24) * 192 + c];
    else if (o < 240) v = Wv[(o - 48) * 192 + c];
    Wbf[idx] = f2bf(v);
  }
  if (idx < 256) {
    float v = 0.f;
    if (idx < 24) v = bq[idx] * LOG2E;
    else if (idx < 48) v = bk[idx - 24];
    else if (idx < 240) v = bv[idx - 48];
    bias[idx] = v;
  }
}

// ---------------- kernel 1: qkv = W_cat . rgb  (MFMA 32x32x16 bf16) -------
// q_ws,k_ws: (B,N,32) bf16 rows (cols 24..31 zeroed). v_ws: (B,192,N) fp8 e4m3.
__global__ __launch_bounds__(256, 2)
void k_qkv(const float* __restrict__ rIn, const float* __restrict__ gIn,
           const float* __restrict__ bIn,
           const ushort_t* __restrict__ Wbf, const float* __restrict__ bias,
           ushort_t* __restrict__ q_ws, ushort_t* __restrict__ k_ws,
           unsigned char* __restrict__ v_ws) {
  __shared__ __align__(16) ushort_t lds[64 * 200];  // [n][c] transposed tile
  int blk = blockIdx.x;
  int bb = blk / NKT, nt = blk % NKT;
  int n0 = nt * 64;
  int t = threadIdx.x;
  {
    int n4 = (t & 15) * 4;
    int c0 = (t >> 4) * 2;
#pragma unroll
    for (int it = 0; it < 6; ++it) {
      int c = c0 + it * 32;
      int color = c >> 6, cw = c & 63;
      const float* base = color == 0 ? rIn : (color == 1 ? gIn : bIn);
      const float* p0 = base + ((size_t)bb * 64 + cw) * NPIX + n0 + n4;
      float4 va = *(const float4*)p0;
      float4 vb = *(const float4*)(p0 + NPIX);
      const float* ap = (const float*)&va;
      const float* bp = (const float*)&vb;
#pragma unroll
      for (int j = 0; j < 4; ++j) {
        unsigned u = ((unsigned)f2bf(bp[j]) << 16) | (unsigned)f2bf(ap[j]);
        *(unsigned*)((char*)lds + (size_t)((n4 + j) * 200 + c) * 2) = u;
      }
    }
  }
  __syncthreads();
  int w = t >> 6, l = t & 63, lo = l & 31, h = l >> 5;
  f32x16 acc[2][2] = {{{}, {}}, {{}, {}}};
  int oG[2] = {(2 * w + 0) * 32 + lo, (2 * w + 1) * 32 + lo};
#pragma unroll 1
  for (int cc = 0; cc < 12; ++cc) {
    bf16x8 af[2], bfr[2];
#pragma unroll
    for (int i = 0; i < 2; ++i)
      af[i] = *(const bf16x8*)((const char*)Wbf + (size_t)oG[i] * 384 + cc * 32 + 16 * h);
#pragma unroll
    for (int ns = 0; ns < 2; ++ns)
      bfr[ns] = *(const bf16x8*)((const char*)lds + (size_t)(ns * 32 + lo) * 400 + cc * 32 + 16 * h);
#pragma unroll
    for (int i = 0; i < 2; ++i)
#pragma unroll
      for (int ns = 0; ns < 2; ++ns)
        acc[i][ns] = __builtin_amdgcn_mfma_f32_32x32x16_bf16(af[i], bfr[ns], acc[i][ns], 0, 0, 0);
  }
#pragma unroll
  for (int i = 0; i < 2; ++i) {
    int o = oG[i];
    float bv = bias[o];
#pragma unroll
    for (int ns = 0; ns < 2; ++ns) {
      if (o < 32) {
#pragma unroll
        for (int r = 0; r < 16; ++r) {
          int n = n0 + ns * 32 + (r & 3) + 8 * (r >> 2) + 4 * h;
          ushort_t val = (o < 24) ? f2bf(acc[i][ns][r] + bv) : (ushort_t)0;
          q_ws[((size_t)bb * NPIX + n) * 32 + o] = val;
        }
      }
      if (o >= 24 && o < 56) {
        int kc = o - 24;
#pragma unroll
        for (int r = 0; r < 16; ++r) {
          int n = n0 + ns * 32 + (r & 3) + 8 * (r >> 2) + 4 * h;
          ushort_t val = (o < 48) ? f2bf(acc[i][ns][r] + bv) : (ushort_t)0;
          k_ws[((size_t)bb * NPIX + n) * 32 + kc] = val;
        }
      }
      if (o >= 48 && o < 240) {
        int vc = o - 48;
#pragma unroll
        for (int g2 = 0; g2 < 4; ++g2) {
          int r = g2 * 4;
          int n = n0 + ns * 32 + 8 * g2 + 4 * h;
          unsigned wd = (unsigned)__builtin_amdgcn_cvt_pk_fp8_f32(
              acc[i][ns][r] + bv, acc[i][ns][r + 1] + bv, 0, false);
          wd = (unsigned)__builtin_amdgcn_cvt_pk_fp8_f32(
              acc[i][ns][r + 2] + bv, acc[i][ns][r + 3] + bv, (int)wd, true);
          *(unsigned*)(v_ws + ((size_t)bb * 192 + vc) * NPIX + n) = wd;
        }
      }
    }
  }
}

// ---------------- kernel 2: flash attention, one key segment --------------
// LDS (36864B): V dbuf [192 c][64B keys] @0/@12288
//               P dbuf [96 q][64B fp8]   @24576/@30720
// Rows are 64B = 4 x 16B chunks; logical chunk c16 stored at c16^((row>>1)&3).
// K straight from global into regs (coalesced, L2-resident).
__global__ __launch_bounds__(512, 6)
void k_attn(const ushort_t* __restrict__ q_ws, const ushort_t* __restrict__ k_ws,
            const unsigned char* __restrict__ v_ws,
            ushort_t* __restrict__ opart, float* __restrict__ lpart,
            int S, int ktPer) {
  __shared__ __align__(16) char smem[36864];
  int id = blockIdx.x;
  int twoS = 2 * S;
  int e = id % twoS, qt = id / twoS;  // id%8 ~ XCD -> per-XCD K/V L2 locality
  int bb = e / S, sg = e % S;
  int q0 = qt * 96;
  int t = threadIdx.x, w = t >> 6, l = t & 63, ql = l & 15, g = l >> 4;
  int ks = w & 3, qh = w >> 2;        // QK roles: keys 16ks.., q 48qh..
  int qg = w & 1, cg = w >> 1;        // PV roles: 48 q x 48 c

  const char* qb = (const char*)q_ws + (size_t)bb * NPIX * 64;
  const char* kb = (const char*)k_ws + (size_t)bb * NPIX * 64;
  const unsigned char* vb = v_ws + (size_t)bb * 192 * NPIX;

  // Q B-frags: q = q0 + qh*48 + 16j + ql, d-chunk g (12 VGPR)
  bf16x8 qf[3];
#pragma unroll
  for (int j = 0; j < 3; ++j)
    qf[j] = *(const bf16x8*)(qb + (size_t)(q0 + qh * 48 + j * 16 + ql) * 64 + g * 16);

  // V staging source offsets (chunk swizzle folded into source; dest linear)
  int c1 = t >> 2, p1 = t & 3;
  int vgo1 = c1 * NPIX + ((p1 ^ ((c1 >> 1) & 3)) << 4);
  int t2 = 512 + t, c2 = t2 >> 2, p2 = t2 & 3;
  int vgo2 = c2 * NPIX + ((p2 ^ ((c2 >> 1) & 3)) << 4);  // used by waves 0..3

  // K global read offset: key = keybase + 16ks + ql, d-chunk g
  int kgo = (16 * ks + ql) * 64 + g * 16;
  // P write: row qh*48+16j+ql; chunk ks^((ql>>1)&3); dword g
  int pwO = (qh * 48 + ql) * 64 + ((ks ^ ((ql >> 1) & 3)) << 4) + 4 * g;
  // PV read bases: +qs/ct*1024 + xo[m]
  int aB = (qg * 48 + ql) * 64 + 8 * (g & 1);
  int bB = (cg * 48 + ql) * 64 + 8 * (g & 1);
  int xo0 = (((g >> 1) ^ ((ql >> 1) & 3)) << 4);          // m=0 chunk
  int xo1 = (((2 + (g >> 1)) ^ ((ql >> 1) & 3)) << 4);    // m=1 chunk

  int kbase = sg * ktPer * 64;  // first key of this segment

  f32x4 oacc[9];  // [qs*3 + ct]
#pragma unroll
  for (int i = 0; i < 9; ++i) oacc[i] = f32x4{0.f, 0.f, 0.f, 0.f};
  float ls[3] = {0.f, 0.f, 0.f};

#define QK_PHASE(PBASE)                                                        \
  {                                                                            \
    _Pragma("unroll")                                                          \
    for (int j = 0; j < 3; ++j) {                                              \
      f32x4 s = f32x4{0.f, 0.f, 0.f, 0.f};                                     \
      s = __builtin_amdgcn_mfma_f32_16x16x32_bf16(kf, qf[j], s, 0, 0, 0);      \
      float p0 = fast_exp2(s[0]), p1 = fast_exp2(s[1]);                        \
      float p2 = fast_exp2(s[2]), p3 = fast_exp2(s[3]);                        \
      ls[j] += (p0 + p1) + (p2 + p3);                                          \
      unsigned uu =                                                            \
          (unsigned)__builtin_amdgcn_cvt_pk_fp8_f32(p0, p1, 0, false);         \
      uu = (unsigned)__builtin_amdgcn_cvt_pk_fp8_f32(p2, p3, (int)uu, true);   \
      *(unsigned*)(smem + (PBASE) + pwO + j * 1024) = uu;                      \
    }                                                                          \
  }

  {  // prologue: stage V(0), load K(0), QK(0) -> P[0]
    const unsigned char* vp = vb + kbase;
    gload_lds16(vp + vgo1, smem + w * 1024 + (l << 4));
    if (w < 4) gload_lds16(vp + vgo2, smem + 8192 + w * 1024 + (l << 4));
    bf16x8 kf = *(const bf16x8*)(kb + (size_t)kbase * 64 + kgo);
    QK_PHASE(24576)
  }
  __syncthreads();  // P[0] visible; V(0) DMA drained

#pragma unroll 1
  for (int it = 0; it < ktPer; ++it) {
    int par = it & 1;
    bf16x8 kf;
    bool more = (it + 1 < ktPer);
    if (more) {  // K(it+1) -> regs; V(it+1) -> V[par^1] (DMA)
      int kb1 = kbase + (it + 1) * 64;
      kf = *(const bf16x8*)(kb + (size_t)kb1 * 64 + kgo);
      const unsigned char* vp = vb + kb1;
      char* vdst = smem + (par ^ 1) * 12288;
      gload_lds16(vp + vgo1, vdst + w * 1024 + (l << 4));
      if (w < 4) gload_lds16(vp + vgo2, vdst + 8192 + w * 1024 + (l << 4));
    }
    // ---- PV(it): 48 q x 48 c per wave from P[par], V[par] ----
    {
      const char* pbuf = smem + 24576 + par * 6144 + aB;
      const char* vbuf = smem + par * 12288 + bB;
      __builtin_amdgcn_s_setprio(1);
#pragma unroll
      for (int m = 0; m < 2; ++m) {
        int xo = m ? xo1 : xo0;
        long A0 = *(const long*)(pbuf + 0 * 1024 + xo);
        long A1 = *(const long*)(pbuf + 1 * 1024 + xo);
        long A2 = *(const long*)(pbuf + 2 * 1024 + xo);
        long B0 = *(const long*)(vbuf + 0 * 1024 + xo);
        long B1 = *(const long*)(vbuf + 1 * 1024 + xo);
        long B2 = *(const long*)(vbuf + 2 * 1024 + xo);
        oacc[0] = __builtin_amdgcn_mfma_f32_16x16x32_fp8_fp8(A0, B0, oacc[0], 0, 0, 0);
        oacc[1] = __builtin_amdgcn_mfma_f32_16x16x32_fp8_fp8(A0, B1, oacc[1], 0, 0, 0);
        oacc[2] = __builtin_amdgcn_mfma_f32_16x16x32_fp8_fp8(A0, B2, oacc[2], 0, 0, 0);
        oacc[3] = __builtin_amdgcn_mfma_f32_16x16x32_fp8_fp8(A1, B0, oacc[3], 0, 0, 0);
        oacc[4] = __builtin_amdgcn_mfma_f32_16x16x32_fp8_fp8(A1, B1, oacc[4], 0, 0, 0);
        oacc[5] = __builtin_amdgcn_mfma_f32_16x16x32_fp8_fp8(A1, B2, oacc[5], 0, 0, 0);
        oacc[6] = __builtin_amdgcn_mfma_f32_16x16x32_fp8_fp8(A2, B0, oacc[6], 0, 0, 0);
        oacc[7] = __builtin_amdgcn_mfma_f32_16x16x32_fp8_fp8(A2, B1, oacc[7], 0, 0, 0);
        oacc[8] = __builtin_amdgcn_mfma_f32_16x16x32_fp8_fp8(A2, B2, oacc[8], 0, 0, 0);
      }
      __builtin_amdgcn_s_setprio(0);
    }
    // ---- QK(it+1) -> P[par^1] (independent of PV(it)) ----
    if (more) QK_PHASE(24576 + (par ^ 1) * 6144)
    __syncthreads();  // P[par^1] visible; V(it+1) DMA drained; P/V[par] free
  }
#undef QK_PHASE

  // ---- lsum: reduce over g (shfl), then over 4 ks-waves via LDS ----
  float* tbl = (float*)(smem + 24576);  // [8 waves][48 q] overlays P
#pragma unroll
  for (int j = 0; j < 3; ++j) {
    float v = ls[j];
    v += __shfl_xor(v, 16);
    v += __shfl_xor(v, 32);
    if (l < 16) tbl[w * 48 + j * 16 + ql] = v;
  }
  __syncthreads();
  if (t < 96) {
    int qhh = t / 48, rr = t % 48;
    float s = 0.f;
#pragma unroll
    for (int k2 = 0; k2 < 4; ++k2) s += tbl[(qhh * 4 + k2) * 48 + rr];
    lpart[(size_t)(sg * 2 + bb) * NPIX + q0 + t] = s;
  }

  // ---- store O partials: lane holds O[q=qs*16+4g+r][c=cg*48+ct*16+ql] ----
  ushort_t* ob = opart + (size_t)(sg * 2 + bb) * 192 * NPIX;
#pragma unroll
  for (int qs = 0; qs < 3; ++qs)
#pragma unroll
    for (int ct = 0; ct < 3; ++ct) {
      f32x4 o = oacc[qs * 3 + ct];
      u64 pk = (u64)f2bf(o[0]) | ((u64)f2bf(o[1]) << 16)
             | ((u64)f2bf(o[2]) << 32) | ((u64)f2bf(o[3]) << 48);
      *(u64*)(ob + (size_t)(cg * 48 + ct * 16 + ql) * NPIX
              + q0 + qg * 48 + qs * 16 + 4 * g) = pk;
    }
}

// ---------------- kernel 3: combine partials + residual -------------------
__global__ __launch_bounds__(256, 8)
void k_comb(const ushort_t* __restrict__ opart, const float* __restrict__ lpart,
            const float* __restrict__ rIn, const float* __restrict__ gIn,
            const float* __restrict__ bIn, float* __restrict__ out, int S) {
  int tg = blockIdx.x * 256 + threadIdx.x;   // 442368 threads: (bb,c) x n8
  int n8 = tg % 1152, row = tg / 1152;       // row in [0,384)
  int bb = row / 192, c = row % 192;
  int n = n8 * 8;
  float acc[8] = {0.f, 0.f, 0.f, 0.f, 0.f, 0.f, 0.f, 0.f};
  float lt[8] = {0.f, 0.f, 0.f, 0.f, 0.f, 0.f, 0.f, 0.f};
#pragma unroll 1
  for (int sg = 0; sg < S; ++sg) {
    const ushort_t* p = opart + ((size_t)(sg * 2 + bb) * 192 + c) * NPIX + n;
    uint4v u = *(const uint4v*)p;
    const ushort_t* us = (const ushort_t*)&u;
#pragma unroll
    for (int j = 0; j < 8; ++j) acc[j] += bf2f(us[j]);
    const float* lp = lpart + (size_t)(sg * 2 + bb) * NPIX + n;
    float4 l0 = *(const float4*)lp;
    float4 l1 = *(const float4*)(lp + 4);
    lt[0] += l0.x; lt[1] += l0.y; lt[2] += l0.z; lt[3] += l0.w;
    lt[4] += l1.x; lt[5] += l1.y; lt[6] += l1.z; lt[7] += l1.w;
  }
  int color = c >> 6, cw = c & 63;
  const float* base = color == 0 ? rIn : (color == 1 ? gIn : bIn);
  const float* rp = base + ((size_t)bb * 64 + cw) * NPIX + n;
  float4 r0 = *(const float4*)rp;
  float4 r1 = *(const float4*)(rp + 4);
  float o[8];
  o[0] = r0.x + acc[0] / lt[0]; o[1] = r0.y + acc[1] / lt[1];
  o[2] = r0.z + acc[2] / lt[2]; o[3] = r0.w + acc[3] / lt[3];
  o[4] = r1.x + acc[4] / lt[4]; o[5] = r1.y + acc[5] / lt[5];
  o[6] = r1.z + acc[6] / lt[6]; o[7] = r1.w + acc[7] / lt[7];
  float* op = out + ((size_t)(color * 2 + bb) * 64 + cw) * NPIX + n;
  *(float4*)op = {o[0], o[1], o[2], o[3]};
  *(float4*)(op + 4) = {o[4], o[5], o[6], o[7]};
}

// ---------------- launcher -------------------------------------------------
extern "C" void kernel_launch(void* const* d_in, const int* in_sizes, int n_in,
                              void* d_out, int out_size, void* d_ws, size_t ws_size,
                              hipStream_t stream) {
  const float* r  = (const float*)d_in[0];
  const float* g  = (const float*)d_in[1];
  const float* b  = (const float*)d_in[2];
  const float* Wq = (const float*)d_in[3];
  const float* bq = (const float*)d_in[4];
  const float* Wk = (const float*)d_in[5];
  const float* bk = (const float*)d_in[6];
  const float* Wv = (const float*)d_in[7];
  const float* bv = (const float*)d_in[8];

  char* ws = (char*)d_ws;
  ushort_t* Wbf = (ushort_t*)(ws);                       //  98304 B
  float* bias   = (float*)(ws + 98304);                  //   1024 B
  ushort_t* q_ws = (ushort_t*)(ws + 99328);              // 1179648 B
  ushort_t* k_ws = (ushort_t*)(ws + 99328 + 1179648);    // 1179648 B
  unsigned char* v_ws = (unsigned char*)(ws + 99328 + 2 * 1179648);  // 3538944 B
  const size_t qkvEnd = 99328 + 2 * 1179648 + 3538944;   // 5997568
  const size_t perS = (size_t)2 * 192 * NPIX * 2 + (size_t)2 * NPIX * 4;  // 7151616

  int S = 8;
  while (S > 1 && qkvEnd + (size_t)S * perS > ws_size) S >>= 1;
  size_t opartSz = (size_t)S * 2 * 192 * NPIX * 2;
  ushort_t* opart = (ushort_t*)(ws + qkvEnd);
  float* lpart = (float*)(ws + qkvEnd + opartSz);

  k_prep<<<192, 256, 0, stream>>>(Wq, bq, Wk, bk, Wv, bv, Wbf, bias);
  k_qkv<<<2 * NKT, 256, 0, stream>>>(r, g, b, Wbf, bias, q_ws, k_ws, v_ws);
  k_attn<<<QT96 * 2 * S, 512, 0, stream>>>(q_ws, k_ws, v_ws, opart, lpart, S, NPIX / 64 / S);
  k_comb<<<1728, 256, 0, stream>>>(opart, lpart, r, g, b, (float*)d_out, S);
}

// Round 13
// 105.895 us; speedup vs baseline: 4.0792x; 1.0974x over previous
//
#include <hip/hip_runtime.h>
#include <hip/hip_bf16.h>

// CrossChannelAttention: B=2, C=64, H=W=96 -> N=9216, NF=192, RD=24.
// k_qkv (MFMA projections) -> k_attn (S key-segments, flash partials) ->
// k_comb (sum/normalize/residual).
// k_attn v13 = v10 VERBATIM (last green structure) with S=4:
//   grid 768 = exactly 3 blocks/CU x 256 CU (zero tail); opart traffic
//   halves in k_attn (write) and k_comb (read).
// v11/v12's ring+counted-vmcnt raced (NaN) twice -> reverted; __syncthreads
// (full vmcnt+lgkm drain) is the verified sync for gload_lds staging here.

#define NPIX 9216
#define NKT 144     // 64-key tiles (k_qkv granularity)
#define QT96 96     // 96-row q-tiles per batch

typedef unsigned short ushort_t;
typedef unsigned long long u64;
typedef __attribute__((ext_vector_type(8))) short bf16x8;
typedef __attribute__((ext_vector_type(4))) float f32x4;
typedef __attribute__((ext_vector_type(16))) float f32x16;
typedef __attribute__((ext_vector_type(4))) unsigned int uint4v;

__device__ inline ushort_t f2bf(float x) {
  __hip_bfloat16 h = __float2bfloat16(x);
  return *reinterpret_cast<ushort_t*>(&h);
}
__device__ inline float bf2f(ushort_t u) {
  unsigned v = ((unsigned)u) << 16;
  return *reinterpret_cast<float*>(&v);
}
__device__ inline float fast_exp2(float x) {
#if __has_builtin(__builtin_amdgcn_exp2f)
  return __builtin_amdgcn_exp2f(x);
#else
  return exp2f(x);
#endif
}
__device__ inline void gload_lds16(const void* g, void* l) {
  __builtin_amdgcn_global_load_lds(
      (const __attribute__((address_space(1))) void*)g,
      (__attribute__((address_space(3))) void*)l, 16, 0, 0);
}

// ---------------- kernel 0: pack W_cat (256x192 bf16) + bias_cat ----------
__global__ void k_prep(const float* __restrict__ Wq, const float* __restrict__ bq,
                       const float* __restrict__ Wk, const float* __restrict__ bk,
                       const float* __restrict__ Wv, const float* __restrict__ bv,
                       ushort_t* __restrict__ Wbf, float* __restrict__ bias) {
  const float LOG2E = 1.4426950408889634f;
  int idx = blockIdx.x * 256 + threadIdx.x;
  if (idx < 256 * 192) {
    int o = idx / 192, c = idx % 192;
    float v = 0.f;
    if (o < 24) v = Wq[o * 192 + c] * LOG2E;
    else if (o < 48) v = Wk[(o - 24) * 192 + c];
    else if (o < 240) v = Wv[(o - 48) * 192 + c];
    Wbf[idx] = f2bf(v);
  }
  if (idx < 256) {
    float v = 0.f;
    if (idx < 24) v = bq[idx] * LOG2E;
    else if (idx < 48) v = bk[idx - 24];
    else if (idx < 240) v = bv[idx - 48];
    bias[idx] = v;
  }
}

// ---------------- kernel 1: qkv = W_cat . rgb  (MFMA 32x32x16 bf16) -------
// q_ws,k_ws: (B,N,32) bf16 rows (cols 24..31 zeroed). v_ws: (B,192,N) fp8 e4m3.
__global__ __launch_bounds__(256, 2)
void k_qkv(const float* __restrict__ rIn, const float* __restrict__ gIn,
           const float* __restrict__ bIn,
           const ushort_t* __restrict__ Wbf, const float* __restrict__ bias,
           ushort_t* __restrict__ q_ws, ushort_t* __restrict__ k_ws,
           unsigned char* __restrict__ v_ws) {
  __shared__ __align__(16) ushort_t lds[64 * 200];  // [n][c] transposed tile
  int blk = blockIdx.x;
  int bb = blk / NKT, nt = blk % NKT;
  int n0 = nt * 64;
  int t = threadIdx.x;
  {
    int n4 = (t & 15) * 4;
    int c0 = (t >> 4) * 2;
#pragma unroll
    for (int it = 0; it < 6; ++it) {
      int c = c0 + it * 32;
      int color = c >> 6, cw = c & 63;
      const float* base = color == 0 ? rIn : (color == 1 ? gIn : bIn);
      const float* p0 = base + ((size_t)bb * 64 + cw) * NPIX + n0 + n4;
      float4 va = *(const float4*)p0;
      float4 vb = *(const float4*)(p0 + NPIX);
      const float* ap = (const float*)&va;
      const float* bp = (const float*)&vb;
#pragma unroll
      for (int j = 0; j < 4; ++j) {
        unsigned u = ((unsigned)f2bf(bp[j]) << 16) | (unsigned)f2bf(ap[j]);
        *(unsigned*)((char*)lds + (size_t)((n4 + j) * 200 + c) * 2) = u;
      }
    }
  }
  __syncthreads();
  int w = t >> 6, l = t & 63, lo = l & 31, h = l >> 5;
  f32x16 acc[2][2] = {{{}, {}}, {{}, {}}};
  int oG[2] = {(2 * w + 0) * 32 + lo, (2 * w + 1) * 32 + lo};
#pragma unroll 1
  for (int cc = 0; cc < 12; ++cc) {
    bf16x8 af[2], bfr[2];
#pragma unroll
    for (int i = 0; i < 2; ++i)
      af[i] = *(const bf16x8*)((const char*)Wbf + (size_t)oG[i] * 384 + cc * 32 + 16 * h);
#pragma unroll
    for (int ns = 0; ns < 2; ++ns)
      bfr[ns] = *(const bf16x8*)((const char*)lds + (size_t)(ns * 32 + lo) * 400 + cc * 32 + 16 * h);
#pragma unroll
    for (int i = 0; i < 2; ++i)
#pragma unroll
      for (int ns = 0; ns < 2; ++ns)
        acc[i][ns] = __builtin_amdgcn_mfma_f32_32x32x16_bf16(af[i], bfr[ns], acc[i][ns], 0, 0, 0);
  }
#pragma unroll
  for (int i = 0; i < 2; ++i) {
    int o = oG[i];
    float bv = bias[o];
#pragma unroll
    for (int ns = 0; ns < 2; ++ns) {
      if (o < 32) {
#pragma unroll
        for (int r = 0; r < 16; ++r) {
          int n = n0 + ns * 32 + (r & 3) + 8 * (r >> 2) + 4 * h;
          ushort_t val = (o < 24) ? f2bf(acc[i][ns][r] + bv) : (ushort_t)0;
          q_ws[((size_t)bb * NPIX + n) * 32 + o] = val;
        }
      }
      if (o >= 24 && o < 56) {
        int kc = o - 24;
#pragma unroll
        for (int r = 0; r < 16; ++r) {
          int n = n0 + ns * 32 + (r & 3) + 8 * (r >> 2) + 4 * h;
          ushort_t val = (o < 48) ? f2bf(acc[i][ns][r] + bv) : (ushort_t)0;
          k_ws[((size_t)bb * NPIX + n) * 32 + kc] = val;
        }
      }
      if (o >= 48 && o < 240) {
        int vc = o - 48;
#pragma unroll
        for (int g2 = 0; g2 < 4; ++g2) {
          int r = g2 * 4;
          int n = n0 + ns * 32 + 8 * g2 + 4 * h;
          unsigned wd = (unsigned)__builtin_amdgcn_cvt_pk_fp8_f32(
              acc[i][ns][r] + bv, acc[i][ns][r + 1] + bv, 0, false);
          wd = (unsigned)__builtin_amdgcn_cvt_pk_fp8_f32(
              acc[i][ns][r + 2] + bv, acc[i][ns][r + 3] + bv, (int)wd, true);
          *(unsigned*)(v_ws + ((size_t)bb * 192 + vc) * NPIX + n) = wd;
        }
      }
    }
  }
}

// ---------------- kernel 2: flash attention, one key segment --------------
// LDS (36864B): V dbuf [192 c][64B keys] @0/@12288
//               P dbuf [96 q][64B fp8]   @24576/@30720
// Rows are 64B = 4 x 16B chunks; logical chunk c16 stored at c16^((row>>1)&3).
// K straight from global into regs (coalesced, L2-resident).
__global__ __launch_bounds__(512, 6)
void k_attn(const ushort_t* __restrict__ q_ws, const ushort_t* __restrict__ k_ws,
            const unsigned char* __restrict__ v_ws,
            ushort_t* __restrict__ opart, float* __restrict__ lpart,
            int S, int ktPer) {
  __shared__ __align__(16) char smem[36864];
  int id = blockIdx.x;
  int twoS = 2 * S;
  int e = id % twoS, qt = id / twoS;  // id%8 ~ XCD -> per-XCD K/V L2 locality
  int bb = e / S, sg = e % S;
  int q0 = qt * 96;
  int t = threadIdx.x, w = t >> 6, l = t & 63, ql = l & 15, g = l >> 4;
  int ks = w & 3, qh = w >> 2;        // QK roles: keys 16ks.., q 48qh..
  int qg = w & 1, cg = w >> 1;        // PV roles: 48 q x 48 c

  const char* qb = (const char*)q_ws + (size_t)bb * NPIX * 64;
  const char* kb = (const char*)k_ws + (size_t)bb * NPIX * 64;
  const unsigned char* vb = v_ws + (size_t)bb * 192 * NPIX;

  // Q B-frags: q = q0 + qh*48 + 16j + ql, d-chunk g (12 VGPR)
  bf16x8 qf[3];
#pragma unroll
  for (int j = 0; j < 3; ++j)
    qf[j] = *(const bf16x8*)(qb + (size_t)(q0 + qh * 48 + j * 16 + ql) * 64 + g * 16);

  // V staging source offsets (chunk swizzle folded into source; dest linear)
  int c1 = t >> 2, p1 = t & 3;
  int vgo1 = c1 * NPIX + ((p1 ^ ((c1 >> 1) & 3)) << 4);
  int t2 = 512 + t, c2 = t2 >> 2, p2 = t2 & 3;
  int vgo2 = c2 * NPIX + ((p2 ^ ((c2 >> 1) & 3)) << 4);  // used by waves 0..3

  // K global read offset: key = keybase + 16ks + ql, d-chunk g
  int kgo = (16 * ks + ql) * 64 + g * 16;
  // P write: row qh*48+16j+ql; chunk ks^((ql>>1)&3); dword g
  int pwO = (qh * 48 + ql) * 64 + ((ks ^ ((ql >> 1) & 3)) << 4) + 4 * g;
  // PV read bases: +qs/ct*1024 + xo[m]
  int aB = (qg * 48 + ql) * 64 + 8 * (g & 1);
  int bB = (cg * 48 + ql) * 64 + 8 * (g & 1);
  int xo0 = (((g >> 1) ^ ((ql >> 1) & 3)) << 4);          // m=0 chunk
  int xo1 = (((2 + (g >> 1)) ^ ((ql >> 1) & 3)) << 4);    // m=1 chunk

  int kbase = sg * ktPer * 64;  // first key of this segment

  f32x4 oacc[9];  // [qs*3 + ct]
#pragma unroll
  for (int i = 0; i < 9; ++i) oacc[i] = f32x4{0.f, 0.f, 0.f, 0.f};
  float ls[3] = {0.f, 0.f, 0.f};

#define QK_PHASE(PBASE)                                                        \
  {                                                                            \
    _Pragma("unroll")                                                          \
    for (int j = 0; j < 3; ++j) {                                              \
      f32x4 s = f32x4{0.f, 0.f, 0.f, 0.f};                                     \
      s = __builtin_amdgcn_mfma_f32_16x16x32_bf16(kf, qf[j], s, 0, 0, 0);      \
      float p0 = fast_exp2(s[0]), p1 = fast_exp2(s[1]);                        \
      float p2 = fast_exp2(s[2]), p3 = fast_exp2(s[3]);                        \
      ls[j] += (p0 + p1) + (p2 + p3);                                          \
      unsigned uu =                                                            \
          (unsigned)__builtin_amdgcn_cvt_pk_fp8_f32(p0, p1, 0, false);         \
      uu = (unsigned)__builtin_amdgcn_cvt_pk_fp8_f32(p2, p3, (int)uu, true);   \
      *(unsigned*)(smem + (PBASE) + pwO + j * 1024) = uu;                      \
    }                                                                          \
  }

  {  // prologue: stage V(0), load K(0), QK(0) -> P[0]
    const unsigned char* vp = vb + kbase;
    gload_lds16(vp + vgo1, smem + w * 1024 + (l << 4));
    if (w < 4) gload_lds16(vp + vgo2, smem + 8192 + w * 1024 + (l << 4));
    bf16x8 kf = *(const bf16x8*)(kb + (size_t)kbase * 64 + kgo);
    QK_PHASE(24576)
  }
  __syncthreads();  // P[0] visible; V(0) DMA drained

#pragma unroll 1
  for (int it = 0; it < ktPer; ++it) {
    int par = it & 1;
    bf16x8 kf;
    bool more = (it + 1 < ktPer);
    if (more) {  // K(it+1) -> regs; V(it+1) -> V[par^1] (DMA)
      int kb1 = kbase + (it + 1) * 64;
      kf = *(const bf16x8*)(kb + (size_t)kb1 * 64 + kgo);
      const unsigned char* vp = vb + kb1;
      char* vdst = smem + (par ^ 1) * 12288;
      gload_lds16(vp + vgo1, vdst + w * 1024 + (l << 4));
      if (w < 4) gload_lds16(vp + vgo2, vdst + 8192 + w * 1024 + (l << 4));
    }
    // ---- PV(it): 48 q x 48 c per wave from P[par], V[par] ----
    {
      const char* pbuf = smem + 24576 + par * 6144 + aB;
      const char* vbuf = smem + par * 12288 + bB;
      __builtin_amdgcn_s_setprio(1);
#pragma unroll
      for (int m = 0; m < 2; ++m) {
        int xo = m ? xo1 : xo0;
        long A0 = *(const long*)(pbuf + 0 * 1024 + xo);
        long A1 = *(const long*)(pbuf + 1 * 1024 + xo);
        long A2 = *(const long*)(pbuf + 2 * 1024 + xo);
        long B0 = *(const long*)(vbuf + 0 * 1024 + xo);
        long B1 = *(const long*)(vbuf + 1 * 1024 + xo);
        long B2 = *(const long*)(vbuf + 2 * 1024 + xo);
        oacc[0] = __builtin_amdgcn_mfma_f32_16x16x32_fp8_fp8(A0, B0, oacc[0], 0, 0, 0);
        oacc[1] = __builtin_amdgcn_mfma_f32_16x16x32_fp8_fp8(A0, B1, oacc[1], 0, 0, 0);
        oacc[2] = __builtin_amdgcn_mfma_f32_16x16x32_fp8_fp8(A0, B2, oacc[2], 0, 0, 0);
        oacc[3] = __builtin_amdgcn_mfma_f32_16x16x32_fp8_fp8(A1, B0, oacc[3], 0, 0, 0);
        oacc[4] = __builtin_amdgcn_mfma_f32_16x16x32_fp8_fp8(A1, B1, oacc[4], 0, 0, 0);
        oacc[5] = __builtin_amdgcn_mfma_f32_16x16x32_fp8_fp8(A1, B2, oacc[5], 0, 0, 0);
        oacc[6] = __builtin_amdgcn_mfma_f32_16x16x32_fp8_fp8(A2, B0, oacc[6], 0, 0, 0);
        oacc[7] = __builtin_amdgcn_mfma_f32_16x16x32_fp8_fp8(A2, B1, oacc[7], 0, 0, 0);
        oacc[8] = __builtin_amdgcn_mfma_f32_16x16x32_fp8_fp8(A2, B2, oacc[8], 0, 0, 0);
      }
      __builtin_amdgcn_s_setprio(0);
    }
    // ---- QK(it+1) -> P[par^1] (independent of PV(it)) ----
    if (more) QK_PHASE(24576 + (par ^ 1) * 6144)
    __syncthreads();  // P[par^1] visible; V(it+1) DMA drained; P/V[par] free
  }
#undef QK_PHASE

  // ---- lsum: reduce over g (shfl), then over 4 ks-waves via LDS ----
  float* tbl = (float*)(smem + 24576);  // [8 waves][48 q] overlays P
#pragma unroll
  for (int j = 0; j < 3; ++j) {
    float v = ls[j];
    v += __shfl_xor(v, 16);
    v += __shfl_xor(v, 32);
    if (l < 16) tbl[w * 48 + j * 16 + ql] = v;
  }
  __syncthreads();
  if (t < 96) {
    int qhh = t / 48, rr = t % 48;
    float s = 0.f;
#pragma unroll
    for (int k2 = 0; k2 < 4; ++k2) s += tbl[(qhh * 4 + k2) * 48 + rr];
    lpart[(size_t)(sg * 2 + bb) * NPIX + q0 + t] = s;
  }

  // ---- store O partials: lane holds O[q=qs*16+4g+r][c=cg*48+ct*16+ql] ----
  ushort_t* ob = opart + (size_t)(sg * 2 + bb) * 192 * NPIX;
#pragma unroll
  for (int qs = 0; qs < 3; ++qs)
#pragma unroll
    for (int ct = 0; ct < 3; ++ct) {
      f32x4 o = oacc[qs * 3 + ct];
      u64 pk = (u64)f2bf(o[0]) | ((u64)f2bf(o[1]) << 16)
             | ((u64)f2bf(o[2]) << 32) | ((u64)f2bf(o[3]) << 48);
      *(u64*)(ob + (size_t)(cg * 48 + ct * 16 + ql) * NPIX
              + q0 + qg * 48 + qs * 16 + 4 * g) = pk;
    }
}

// ---------------- kernel 3: combine partials + residual -------------------
__global__ __launch_bounds__(256, 8)
void k_comb(const ushort_t* __restrict__ opart, const float* __restrict__ lpart,
            const float* __restrict__ rIn, const float* __restrict__ gIn,
            const float* __restrict__ bIn, float* __restrict__ out, int S) {
  int tg = blockIdx.x * 256 + threadIdx.x;   // 442368 threads: (bb,c) x n8
  int n8 = tg % 1152, row = tg / 1152;       // row in [0,384)
  int bb = row / 192, c = row % 192;
  int n = n8 * 8;
  float acc[8] = {0.f, 0.f, 0.f, 0.f, 0.f, 0.f, 0.f, 0.f};
  float lt[8] = {0.f, 0.f, 0.f, 0.f, 0.f, 0.f, 0.f, 0.f};
#pragma unroll 1
  for (int sg = 0; sg < S; ++sg) {
    const ushort_t* p = opart + ((size_t)(sg * 2 + bb) * 192 + c) * NPIX + n;
    uint4v u = *(const uint4v*)p;
    const ushort_t* us = (const ushort_t*)&u;
#pragma unroll
    for (int j = 0; j < 8; ++j) acc[j] += bf2f(us[j]);
    const float* lp = lpart + (size_t)(sg * 2 + bb) * NPIX + n;
    float4 l0 = *(const float4*)lp;
    float4 l1 = *(const float4*)(lp + 4);
    lt[0] += l0.x; lt[1] += l0.y; lt[2] += l0.z; lt[3] += l0.w;
    lt[4] += l1.x; lt[5] += l1.y; lt[6] += l1.z; lt[7] += l1.w;
  }
  int color = c >> 6, cw = c & 63;
  const float* base = color == 0 ? rIn : (color == 1 ? gIn : bIn);
  const float* rp = base + ((size_t)bb * 64 + cw) * NPIX + n;
  float4 r0 = *(const float4*)rp;
  float4 r1 = *(const float4*)(rp + 4);
  float o[8];
  o[0] = r0.x + acc[0] / lt[0]; o[1] = r0.y + acc[1] / lt[1];
  o[2] = r0.z + acc[2] / lt[2]; o[3] = r0.w + acc[3] / lt[3];
  o[4] = r1.x + acc[4] / lt[4]; o[5] = r1.y + acc[5] / lt[5];
  o[6] = r1.z + acc[6] / lt[6]; o[7] = r1.w + acc[7] / lt[7];
  float* op = out + ((size_t)(color * 2 + bb) * 64 + cw) * NPIX + n;
  *(float4*)op = {o[0], o[1], o[2], o[3]};
  *(float4*)(op + 4) = {o[4], o[5], o[6], o[7]};
}

// ---------------- launcher -------------------------------------------------
extern "C" void kernel_launch(void* const* d_in, const int* in_sizes, int n_in,
                              void* d_out, int out_size, void* d_ws, size_t ws_size,
                              hipStream_t stream) {
  const float* r  = (const float*)d_in[0];
  const float* g  = (const float*)d_in[1];
  const float* b  = (const float*)d_in[2];
  const float* Wq = (const float*)d_in[3];
  const float* bq = (const float*)d_in[4];
  const float* Wk = (const float*)d_in[5];
  const float* bk = (const float*)d_in[6];
  const float* Wv = (const float*)d_in[7];
  const float* bv = (const float*)d_in[8];

  char* ws = (char*)d_ws;
  ushort_t* Wbf = (ushort_t*)(ws);                       //  98304 B
  float* bias   = (float*)(ws + 98304);                  //   1024 B
  ushort_t* q_ws = (ushort_t*)(ws + 99328);              // 1179648 B
  ushort_t* k_ws = (ushort_t*)(ws + 99328 + 1179648);    // 1179648 B
  unsigned char* v_ws = (unsigned char*)(ws + 99328 + 2 * 1179648);  // 3538944 B
  const size_t qkvEnd = 99328 + 2 * 1179648 + 3538944;   // 5997568
  const size_t perS = (size_t)2 * 192 * NPIX * 2 + (size_t)2 * NPIX * 4;  // 7151616

  int S = 4;  // grid 768 = exactly 3 blocks/CU x 256 CU; halves opart traffic
  while (S > 1 && qkvEnd + (size_t)S * perS > ws_size) S >>= 1;
  size_t opartSz = (size_t)S * 2 * 192 * NPIX * 2;
  ushort_t* opart = (ushort_t*)(ws + qkvEnd);
  float* lpart = (float*)(ws + qkvEnd + opartSz);

  k_prep<<<192, 256, 0, stream>>>(Wq, bq, Wk, bk, Wv, bv, Wbf, bias);
  k_qkv<<<2 * NKT, 256, 0, stream>>>(r, g, b, Wbf, bias, q_ws, k_ws, v_ws);
  k_attn<<<QT96 * 2 * S, 512, 0, stream>>>(q_ws, k_ws, v_ws, opart, lpart, S, NPIX / 64 / S);
  k_comb<<<1728, 256, 0, stream>>>(opart, lpart, r, g, b, (float*)d_out, S);
}